// Round 1
// baseline (40.909 us; speedup 1.0000x reference)
//
#include <hip/hip_runtime.h>
#include <hip/hip_bf16.h>
#include <cstdint>
#include <cstddef>

#define IN_DIM 128
#define OUT_DIM 128
#define NB 8
#define KDIM (9 * 128)   // 1152

using bf16 = __hip_bfloat16;
typedef __attribute__((ext_vector_type(8))) short short8;   // 8 bf16 = 4 VGPRs
typedef __attribute__((ext_vector_type(4))) float f32x4;

// ---------------------------------------------------------------------------
// Shared basis math: uniform cubic B-spline, grid knots g0..g11, h uniform.
// For x in [g_j, g_{j+1}), u = t - j, the 4 nonzero cubic basis fns are
// indices m = j-3..j (clipped to [0,7]) with the standard uniform weights.
// ---------------------------------------------------------------------------
__device__ __forceinline__ void basis_weights(float xv, float g0, float inv_h,
                                              int& j, float& w0, float& w1,
                                              float& w2, float& w3) {
    float t = (xv - g0) * inv_h;
    float jf = floorf(t);
    j = (int)jf;
    float u = t - jf;
    float um = 1.f - u;
    float u2 = u * u, u3 = u2 * u;
    w0 = um * um * um * (1.f / 6.f);
    w1 = (3.f * u3 - 6.f * u2 + 4.f) * (1.f / 6.f);
    w2 = (-3.f * u3 + 3.f * u2 + 3.f * u + 1.f) * (1.f / 6.f);
    w3 = u3 * (1.f / 6.f);
}

// ---------------------------------------------------------------------------
// Kernel 1: F[b][k], k = f*128 + i; f=0 -> silu(x), f=1+m -> basis_m(x).
// One thread per (b,i). Stores are lane-contiguous in i (coalesced 128B).
// ---------------------------------------------------------------------------
__global__ void k_features(const float* __restrict__ x,
                           const float* __restrict__ grid,
                           bf16* __restrict__ F) {
    int t = threadIdx.x;
    int b = blockIdx.x * 2 + (t >> 7);
    int i = t & 127;
    float xv = x[(size_t)b * IN_DIM + i];
    float g0 = grid[0];
    float h = grid[4] - grid[3];
    float inv_h = 1.f / h;

    float silu = xv / (1.f + __expf(-xv));

    int j; float w0, w1, w2, w3;
    basis_weights(xv, g0, inv_h, j, w0, w1, w2, w3);
    bool inrange = (j >= 0) && (j < 11);

    bf16* Fb = F + (size_t)b * KDIM;
    Fb[i] = __float2bfloat16(silu);
#pragma unroll
    for (int m = 0; m < 8; ++m) {
        int k2 = m - (j - 3);
        float val = 0.f;
        if (inrange && k2 >= 0 && k2 < 4)
            val = (k2 == 0) ? w0 : (k2 == 1) ? w1 : (k2 == 2) ? w2 : w3;
        Fb[(1 + m) * 128 + i] = __float2bfloat16(val);
    }
}

// ---------------------------------------------------------------------------
// Kernel 2: Wct[o][k] (128 x 1152 bf16), k = f*128+i.
// f=0: base_weight[i][o];  f=1+m: spline_coeff[i][o][m].
// ---------------------------------------------------------------------------
__global__ void k_wc(const float* __restrict__ W, const float* __restrict__ C,
                     bf16* __restrict__ Wct) {
    int t = blockIdx.x * 256 + threadIdx.x;   // 16384 threads
    int i = t & 127;
    int o = t >> 7;
    bf16* row = Wct + (size_t)o * KDIM;
    row[i] = __float2bfloat16(W[(size_t)i * OUT_DIM + o]);
    const float* c = C + ((size_t)i * OUT_DIM + o) * NB;
#pragma unroll
    for (int m = 0; m < 8; ++m)
        row[(1 + m) * 128 + i] = __float2bfloat16(c[m]);
}

// ---------------------------------------------------------------------------
// Kernel 3: GEMM  out[M=8192][N=128] = scale * F[M][K=1152] * Wct^T
// BM=32, BN=128 (full), BK=32. 256 threads = 4 waves in 2x2:
//   wave (wr,wc): rows wr*16..+15, cols wc*64..+63 -> 4 mfma_16x16x32 frags.
// LDS tiles stored as [row][32 k] = 64B rows, 16B chunks XOR-swizzled by
// (row&3) to spread the stride-64B fragment reads across banks.
// ---------------------------------------------------------------------------
__global__ __launch_bounds__(256)
void k_gemm(const bf16* __restrict__ F, const bf16* __restrict__ Wct,
            const float* __restrict__ scale, float* __restrict__ out) {
    __shared__ __align__(16) char smem[(32 * 32 + 128 * 32) * 2];  // 10 KiB
    char* Abase = smem;           // 2048 B : 32 rows x 64 B
    char* Bbase = smem + 2048;    // 8192 B : 128 rows x 64 B

    int tid = threadIdx.x;
    int wave = tid >> 6, lane = tid & 63;
    int wr = wave >> 1, wc = wave & 1;
    int m0 = blockIdx.x * 32;

    f32x4 acc[4];
#pragma unroll
    for (int n = 0; n < 4; ++n) acc[n] = 0.f;

    // fragment read offsets (byte) within A/B LDS regions
    int ar = wr * 16 + (lane & 15);
    int achk = lane >> 4;
    int a_off = ar * 64 + ((achk ^ (ar & 3)) << 4);
    int b_off[4];
#pragma unroll
    for (int n = 0; n < 4; ++n) {
        int orow = wc * 64 + n * 16 + (lane & 15);
        b_off[n] = orow * 64 + (((lane >> 4) ^ (orow & 3)) << 4);
    }

    for (int k0 = 0; k0 < KDIM; k0 += 32) {
        // ---- stage A tile (128 x 16B slots) ----
        if (tid < 128) {
            int row = tid >> 2, chunk = tid & 3;
            float4 v = *(const float4*)(F + ((size_t)(m0 + row)) * KDIM + k0 + chunk * 8);
            *(float4*)(Abase + row * 64 + ((chunk ^ (row & 3)) << 4)) = v;
        }
        // ---- stage B tile (512 x 16B slots) ----
#pragma unroll
        for (int sidx = 0; sidx < 2; ++sidx) {
            int s = tid + sidx * 256;
            int row = s >> 2, chunk = s & 3;
            float4 v = *(const float4*)(Wct + (size_t)row * KDIM + k0 + chunk * 8);
            *(float4*)(Bbase + row * 64 + ((chunk ^ (row & 3)) << 4)) = v;
        }
        __syncthreads();

        short8 af = *(const short8*)(Abase + a_off);
#pragma unroll
        for (int n = 0; n < 4; ++n) {
            short8 bf = *(const short8*)(Bbase + b_off[n]);
            acc[n] = __builtin_amdgcn_mfma_f32_16x16x32_bf16(af, bf, acc[n], 0, 0, 0);
        }
        __syncthreads();
    }

    float s = scale[0];
    int col = lane & 15;
    int rbase = (lane >> 4) * 4;
#pragma unroll
    for (int n = 0; n < 4; ++n) {
        int oc = wc * 64 + n * 16 + col;
#pragma unroll
        for (int r = 0; r < 4; ++r) {
            int row = m0 + wr * 16 + rbase + r;
            out[(size_t)row * OUT_DIM + oc] = acc[n][r] * s;
        }
    }
}

// ---------------------------------------------------------------------------
// Fallback (only if ws too small): fully fused f32, correct but slow.
// ---------------------------------------------------------------------------
__global__ void k_naive(const float* __restrict__ x, const float* __restrict__ grid,
                        const float* __restrict__ C, const float* __restrict__ W,
                        const float* __restrict__ scale, float* __restrict__ out) {
    __shared__ float sS[128];
    __shared__ float sB[128][8];
    int b = blockIdx.x, t = threadIdx.x;   // 128 threads
    float xv = x[(size_t)b * IN_DIM + t];
    float g0 = grid[0];
    float inv_h = 1.f / (grid[4] - grid[3]);
    sS[t] = xv / (1.f + __expf(-xv));
    int j; float w0, w1, w2, w3;
    basis_weights(xv, g0, inv_h, j, w0, w1, w2, w3);
    bool inrange = (j >= 0) && (j < 11);
#pragma unroll
    for (int m = 0; m < 8; ++m) {
        int k2 = m - (j - 3);
        float val = 0.f;
        if (inrange && k2 >= 0 && k2 < 4)
            val = (k2 == 0) ? w0 : (k2 == 1) ? w1 : (k2 == 2) ? w2 : w3;
        sB[t][m] = val;
    }
    __syncthreads();
    float acc = 0.f;
    for (int i = 0; i < IN_DIM; ++i) {
        acc += sS[i] * W[(size_t)i * OUT_DIM + t];
        const float* c = C + ((size_t)i * OUT_DIM + t) * NB;
#pragma unroll
        for (int m = 0; m < 8; ++m) acc += sB[i][m] * c[m];
    }
    out[(size_t)b * OUT_DIM + t] = acc * scale[0];
}

// ---------------------------------------------------------------------------
extern "C" void kernel_launch(void* const* d_in, const int* in_sizes, int n_in,
                              void* d_out, int out_size, void* d_ws, size_t ws_size,
                              hipStream_t stream) {
    const float* x     = (const float*)d_in[0];
    const float* grid  = (const float*)d_in[1];
    const float* C     = (const float*)d_in[2];
    const float* W     = (const float*)d_in[3];
    const float* scale = (const float*)d_in[4];
    float* out = (float*)d_out;

    int B = in_sizes[0] / IN_DIM;   // 8192

    size_t needF = (size_t)B * KDIM * sizeof(bf16);       // 18.9 MB
    size_t needW = (size_t)OUT_DIM * KDIM * sizeof(bf16); // 288 KB

    if (ws_size >= needF + needW && (B % 32) == 0) {
        bf16* F   = (bf16*)d_ws;
        bf16* Wct = (bf16*)((char*)d_ws + needF);
        k_features<<<B / 2, 256, 0, stream>>>(x, grid, F);
        k_wc<<<(OUT_DIM * IN_DIM) / 256, 256, 0, stream>>>(W, C, Wct);
        k_gemm<<<B / 32, 256, 0, stream>>>(F, Wct, scale, out);
    } else {
        k_naive<<<B, 128, 0, stream>>>(x, grid, C, W, scale, out);
    }
}

// Round 2
// 21.850 us; speedup vs baseline: 1.8723x; 1.8723x over previous
//
#include <hip/hip_runtime.h>
#include <hip/hip_bf16.h>
#include <cstdint>
#include <cstddef>

#define IN_DIM 128
#define OUT_DIM 128
#define NB 8
#define KDIM 1152          // 9 features * 128 in-dims, k = f*128 + i
#define BM 32
#define BK 128
#define NT (KDIM / BK)     // 9 K-tiles
#define B_TILE_BYTES (OUT_DIM * BK * 2)   // 32768
#define A_BYTES (BM * KDIM * 2)           // 73728

using bf16 = __hip_bfloat16;
typedef __attribute__((ext_vector_type(8))) short short8;   // 8 bf16
typedef __attribute__((ext_vector_type(4))) float f32x4;

// ---------------------------------------------------------------------------
// Uniform cubic B-spline weights. Grid knots g0..g11 uniform spacing h.
// x in [g_j, g_{j+1}): nonzero cubic basis m = j-3..j (clipped to [0,7]).
// ---------------------------------------------------------------------------
__device__ __forceinline__ void basis_weights(float xv, float g0, float inv_h,
                                              int& j, float& w0, float& w1,
                                              float& w2, float& w3) {
    float t = (xv - g0) * inv_h;
    float jf = floorf(t);
    j = (int)jf;
    float u = t - jf;
    float um = 1.f - u;
    float u2 = u * u, u3 = u2 * u;
    w0 = um * um * um * (1.f / 6.f);
    w1 = (3.f * u3 - 6.f * u2 + 4.f) * (1.f / 6.f);
    w2 = (-3.f * u3 + 3.f * u2 + 3.f * u + 1.f) * (1.f / 6.f);
    w3 = u3 * (1.f / 6.f);
}

__device__ __forceinline__ unsigned short to_bf16_bits(float v) {
    bf16 h = __float2bfloat16(v);
    return *(unsigned short*)&h;
}

// ---------------------------------------------------------------------------
// Kernel 1: Wct[o][k] (128 x 1152 bf16), k = f*128+i.
// f=0: base_weight[i][o];  f=1+m: spline_coeff[i][o][m].
// ---------------------------------------------------------------------------
__global__ void k_wc(const float* __restrict__ W, const float* __restrict__ C,
                     bf16* __restrict__ Wct) {
    int t = blockIdx.x * 256 + threadIdx.x;   // 16384 threads
    int i = t & 127;
    int o = t >> 7;
    bf16* row = Wct + (size_t)o * KDIM;
    row[i] = __float2bfloat16(W[(size_t)i * OUT_DIM + o]);
    const float* c = C + ((size_t)i * OUT_DIM + o) * NB;
#pragma unroll
    for (int m = 0; m < 8; ++m)
        row[(1 + m) * 128 + i] = __float2bfloat16(c[m]);
}

// ---------------------------------------------------------------------------
// Kernel 2 (fused): features -> persistent LDS A tile, then MFMA GEMM vs Wct.
//   out[M=8192][N=128] = scale * A(features)[M][K] * Wct[N][K]^T
// 512 threads = 8 waves (wr = wave>>2 in 0..1, wc = wave&3 in 0..3):
//   wave owns rows wr*16..+15, cols wc*32..+31 (2 n-frags), BK=128 per iter.
// LDS chunks (16B) XOR-swizzled by (row&7) on low 3 chunk bits; residual
// 2-way conflicts are free. B staged by global_load_lds (linear LDS dest,
// pre-swizzled per-lane global source).
// ---------------------------------------------------------------------------
__global__ __launch_bounds__(512)
void k_fused(const float* __restrict__ x, const float* __restrict__ grid,
             const bf16* __restrict__ Wct, const float* __restrict__ scale,
             float* __restrict__ out) {
    __shared__ __align__(16) char smem[A_BYTES + 2 * B_TILE_BYTES];  // 136 KiB
    char* Abase = smem;
    char* Bbase = smem + A_BYTES;

    const int tid = threadIdx.x;
    const int wave = tid >> 6, lane = tid & 63;
    const int m0 = blockIdx.x * BM;

    // ---- stage one B K-tile (32 KB = 2048 16B chunks; 4 instr/wave) ----
    auto stageB = [&](int buf, int t) {
        int k0 = t * BK;
#pragma unroll
        for (int inst = 0; inst < 4; ++inst) {
            int cbase = wave * 256 + inst * 64;       // wave-uniform
            int c = cbase + lane;                     // linear chunk id
            int o = c >> 4;                           // B row (0..127)
            int ch = c & 15;                          // chunk within row
            const bf16* src = Wct + (size_t)o * KDIM + k0 + ((ch ^ (o & 7)) << 3);
            char* dst = Bbase + buf * B_TILE_BYTES + cbase * 16;
            __builtin_amdgcn_global_load_lds(
                (const __attribute__((address_space(1))) void*)src,
                (__attribute__((address_space(3))) void*)dst, 16, 0, 0);
        }
    };
    stageB(0, 0);   // overlap B0 load with feature compute below

    // ---- compute features into persistent A: row=tid>>4, i0=(tid&15)*8 ----
    {
        int row = tid >> 4;       // 0..31
        int ip = tid & 15;        // 0..15
        int i0 = ip * 8;
        const float* xr = x + (size_t)(m0 + row) * IN_DIM + i0;
        float4 xa = *(const float4*)xr;
        float4 xb = *(const float4*)(xr + 4);
        float xv[8] = {xa.x, xa.y, xa.z, xa.w, xb.x, xb.y, xb.z, xb.w};
        float g0 = grid[0];
        float inv_h = 1.f / (grid[4] - grid[3]);

        short8 feat[9];
#pragma unroll
        for (int e = 0; e < 8; ++e) {
            float v = xv[e];
            float sl = v / (1.f + __expf(-v));
            int j; float w0, w1, w2, w3;
            basis_weights(v, g0, inv_h, j, w0, w1, w2, w3);
            bool inr = (j >= 0) && (j < 11);
            feat[0][e] = (short)to_bf16_bits(sl);
#pragma unroll
            for (int m = 0; m < 8; ++m) {
                int k2 = m - (j - 3);
                float val = 0.f;
                if (inr && k2 >= 0 && k2 < 4)
                    val = (k2 == 0) ? w0 : (k2 == 1) ? w1 : (k2 == 2) ? w2 : w3;
                feat[1 + m][e] = (short)to_bf16_bits(val);
            }
        }
        // write 9 x 16B, chunk = (f*16 + ip) ^ (row&7)  (XOR stays in f-group)
#pragma unroll
        for (int f = 0; f < 9; ++f) {
            int chunk = (f * 16 + ip) ^ (row & 7);
            *(short8*)(Abase + row * 2304 + chunk * 16) = feat[f];
        }
    }
    __syncthreads();   // drains vmcnt(0): B0 staged; features visible

    // ---- K loop ----
    const int wr = wave >> 2, wc = wave & 3;
    const int r = wr * 16 + (lane & 15);         // A row this lane reads
    const int arow = r * 2304;
    f32x4 acc[2];
#pragma unroll
    for (int n = 0; n < 2; ++n) acc[n] = 0.f;

    int cur = 0;
    for (int t = 0; t < NT; ++t) {
        if (t + 1 < NT) stageB(cur ^ 1, t + 1);

        short8 a[4], b[2][4];
#pragma unroll
        for (int ks = 0; ks < 4; ++ks) {
            int c = 16 * t + ks * 4 + (lane >> 4);       // logical chunk
            int cs = c ^ (r & 7);                        // swizzled slot
            a[ks] = *(const short8*)(Abase + arow + cs * 16);
        }
#pragma unroll
        for (int n = 0; n < 2; ++n) {
            int o = wc * 32 + n * 16 + (lane & 15);
            const char* Brow = Bbase + cur * B_TILE_BYTES + o * 256;
#pragma unroll
            for (int ks = 0; ks < 4; ++ks) {
                int ch = ks * 4 + (lane >> 4);
                b[n][ks] = *(const short8*)(Brow + (ch ^ (o & 7)) * 16);
            }
        }
#pragma unroll
        for (int ks = 0; ks < 4; ++ks) {
            acc[0] = __builtin_amdgcn_mfma_f32_16x16x32_bf16(a[ks], b[0][ks], acc[0], 0, 0, 0);
            acc[1] = __builtin_amdgcn_mfma_f32_16x16x32_bf16(a[ks], b[1][ks], acc[1], 0, 0, 0);
        }
        __syncthreads();   // vmcnt(0)+barrier: next B tile ready, cur free
        cur ^= 1;
    }

    // ---- epilogue: C/D map col=lane&15, row=(lane>>4)*4+q ----
    float s = scale[0];
    int col0 = wc * 32 + (lane & 15);
    int rbase = m0 + wr * 16 + (lane >> 4) * 4;
#pragma unroll
    for (int n = 0; n < 2; ++n)
#pragma unroll
        for (int q = 0; q < 4; ++q)
            out[(size_t)(rbase + q) * OUT_DIM + col0 + n * 16] = acc[n][q] * s;
}

// ---------------------------------------------------------------------------
// Fallback (only if ws too small): fully fused f32, correct but slow.
// ---------------------------------------------------------------------------
__global__ void k_naive(const float* __restrict__ x, const float* __restrict__ grid,
                        const float* __restrict__ C, const float* __restrict__ W,
                        const float* __restrict__ scale, float* __restrict__ out) {
    __shared__ float sS[128];
    __shared__ float sB[128][8];
    int b = blockIdx.x, t = threadIdx.x;   // 128 threads
    float xv = x[(size_t)b * IN_DIM + t];
    float g0 = grid[0];
    float inv_h = 1.f / (grid[4] - grid[3]);
    sS[t] = xv / (1.f + __expf(-xv));
    int j; float w0, w1, w2, w3;
    basis_weights(xv, g0, inv_h, j, w0, w1, w2, w3);
    bool inrange = (j >= 0) && (j < 11);
#pragma unroll
    for (int m = 0; m < 8; ++m) {
        int k2 = m - (j - 3);
        float val = 0.f;
        if (inrange && k2 >= 0 && k2 < 4)
            val = (k2 == 0) ? w0 : (k2 == 1) ? w1 : (k2 == 2) ? w2 : w3;
        sB[t][m] = val;
    }
    __syncthreads();
    float acc = 0.f;
    for (int i = 0; i < IN_DIM; ++i) {
        acc += sS[i] * W[(size_t)i * OUT_DIM + t];
        const float* c = C + ((size_t)i * OUT_DIM + t) * NB;
#pragma unroll
        for (int m = 0; m < 8; ++m) acc += sB[i][m] * c[m];
    }
    out[(size_t)b * OUT_DIM + t] = acc * scale[0];
}

// ---------------------------------------------------------------------------
extern "C" void kernel_launch(void* const* d_in, const int* in_sizes, int n_in,
                              void* d_out, int out_size, void* d_ws, size_t ws_size,
                              hipStream_t stream) {
    const float* x     = (const float*)d_in[0];
    const float* grid  = (const float*)d_in[1];
    const float* C     = (const float*)d_in[2];
    const float* W     = (const float*)d_in[3];
    const float* scale = (const float*)d_in[4];
    float* out = (float*)d_out;

    int B = in_sizes[0] / IN_DIM;   // 8192

    size_t needW = (size_t)OUT_DIM * KDIM * sizeof(bf16); // 288 KB

    if (ws_size >= needW && (B % BM) == 0) {
        bf16* Wct = (bf16*)d_ws;
        k_wc<<<(OUT_DIM * IN_DIM) / 256, 256, 0, stream>>>(W, C, Wct);
        k_fused<<<B / BM, 512, 0, stream>>>(x, grid, Wct, scale, out);
    } else {
        k_naive<<<B, 128, 0, stream>>>(x, grid, C, W, scale, out);
    }
}

// Round 3
// 21.594 us; speedup vs baseline: 1.8945x; 1.0119x over previous
//
#include <hip/hip_runtime.h>
#include <hip/hip_bf16.h>
#include <cstdint>
#include <cstddef>

#define IN_DIM 128
#define OUT_DIM 128
#define NB 8
#define KDIM 1152          // 9 features * 128 in-dims, k = f*128 + i
#define BM 32
#define BK 128
#define NT (KDIM / BK)     // 9 K-tiles; tile t uses feature f=t exactly
#define B_TILE_BYTES (OUT_DIM * BK * 2)   // 32768
#define A_BYTES (BM * KDIM * 2)           // 73728
#define WG_TILE (OUT_DIM * IN_DIM)        // elements per f-tile of Wg

using bf16 = __hip_bfloat16;
typedef __attribute__((ext_vector_type(8))) short short8;   // 8 bf16
typedef __attribute__((ext_vector_type(4))) float f32x4;

// ---------------------------------------------------------------------------
// Uniform cubic B-spline weights. Grid knots g0..g11 uniform spacing h.
// x in [g_j, g_{j+1}): nonzero cubic basis m = j-3..j (clipped to [0,7]).
// ---------------------------------------------------------------------------
__device__ __forceinline__ void basis_weights(float xv, float g0, float inv_h,
                                              int& j, float& w0, float& w1,
                                              float& w2, float& w3) {
    float t = (xv - g0) * inv_h;
    float jf = floorf(t);
    j = (int)jf;
    float u = t - jf;
    float um = 1.f - u;
    float u2 = u * u, u3 = u2 * u;
    w0 = um * um * um * (1.f / 6.f);
    w1 = (3.f * u3 - 6.f * u2 + 4.f) * (1.f / 6.f);
    w2 = (-3.f * u3 + 3.f * u2 + 3.f * u + 1.f) * (1.f / 6.f);
    w3 = u3 * (1.f / 6.f);
}

__device__ __forceinline__ unsigned short to_bf16_bits(float v) {
    bf16 h = __float2bfloat16(v);
    return *(unsigned short*)&h;
}

// ---------------------------------------------------------------------------
// Kernel 1: Wg[f][o][i] (9 x 128 x 128 bf16), f=0 -> base_weight^T,
// f=1+m -> spline_coeff[:,:,m]^T. LDS transpose: coalesced reads AND writes.
// Grid: 32 blocks x 256 threads; block handles o-tile of 4.
// ---------------------------------------------------------------------------
__global__ void k_wc(const float* __restrict__ W, const float* __restrict__ C,
                     bf16* __restrict__ Wg) {
    __shared__ float sC[128][36];   // [i][o'*8+m], pad 36 (16B-aligned rows)
    __shared__ float sW[128][4];    // [i][o']
    int tid = threadIdx.x;
    int o0 = blockIdx.x * 4;

    // C window: 128 i-rows x 32 floats (4 o x 8 m), contiguous 128B per row
#pragma unroll
    for (int jj = 0; jj < 4; ++jj) {
        int idx = tid + jj * 256;           // 1024 float4
        int i = idx >> 3, q = idx & 7;
        float4 v = *(const float4*)(C + (size_t)i * 1024 + o0 * 8 + q * 4);
        *(float4*)&sC[i][q * 4] = v;
    }
    if (tid < 128) {
        float4 v = *(const float4*)(W + (size_t)tid * 128 + o0);
        *(float4*)&sW[tid][0] = v;
    }
    __syncthreads();

    // 36 output rows (9 f x 4 o'), each 128 i -> 8 chunks of 16 i
    for (int c = tid; c < 288; c += 256) {
        int row = c >> 3, ich = c & 7;
        int f = row >> 2, op = row & 3;
        int i0 = ich * 16;
        short8 lo, hi;
#pragma unroll
        for (int s = 0; s < 8; ++s) {
            float v0 = (f == 0) ? sW[i0 + s][op] : sC[i0 + s][op * 8 + (f - 1)];
            float v1 = (f == 0) ? sW[i0 + 8 + s][op] : sC[i0 + 8 + s][op * 8 + (f - 1)];
            lo[s] = (short)to_bf16_bits(v0);
            hi[s] = (short)to_bf16_bits(v1);
        }
        bf16* dst = Wg + (size_t)f * WG_TILE + (size_t)(o0 + op) * 128 + i0;
        *(short8*)dst = lo;
        *(short8*)(dst + 8) = hi;
    }
}

// ---------------------------------------------------------------------------
// Kernel 2 (fused): features -> persistent LDS A tile, then MFMA GEMM vs Wg.
//   out[M=8192][N=128] = scale * A(features)[M][K] * Wg^T
// 512 threads = 8 waves. ks-split-2: group g = wave>>2 handles K-subslices
// {2g, 2g+1} of each 128-wide K-tile; col-wave w = wave&3 owns cols w*32..+31.
// Each wave: 32x32 output tile over half the K -> 8 ds_read + 8 MFMA / iter
// (LDS bytes per MFMA = 1.0 KB vs 1.5 before). Partial sums reduced via LDS.
// ---------------------------------------------------------------------------
__global__ __launch_bounds__(512)
void k_fused(const float* __restrict__ x, const float* __restrict__ grid,
             const bf16* __restrict__ Wg, const float* __restrict__ scale,
             float* __restrict__ out) {
    __shared__ __align__(16) char smem[A_BYTES + 2 * B_TILE_BYTES];  // 136 KiB
    char* Abase = smem;
    char* Bbase = smem + A_BYTES;

    const int tid = threadIdx.x;
    const int wave = tid >> 6, lane = tid & 63;
    const int m0 = blockIdx.x * BM;

    // ---- stage one B K-tile (32 KB = 2048 16B chunks; 4 instr/wave) ----
    // Wg tile f: [o][i], 256B rows. Linear LDS dest, pre-swizzled global src.
    auto stageB = [&](int buf, int t) {
#pragma unroll
        for (int inst = 0; inst < 4; ++inst) {
            int cbase = wave * 256 + inst * 64;       // wave-uniform
            int c = cbase + lane;                     // linear chunk id
            int o = c >> 4;                           // B row (0..127)
            int ch = c & 15;                          // chunk within row
            const bf16* src = Wg + (size_t)t * WG_TILE + (size_t)o * 128 +
                              ((ch ^ (o & 7)) << 3);
            char* dst = Bbase + buf * B_TILE_BYTES + cbase * 16;
            __builtin_amdgcn_global_load_lds(
                (const __attribute__((address_space(1))) void*)src,
                (__attribute__((address_space(3))) void*)dst, 16, 0, 0);
        }
    };
    stageB(0, 0);   // overlap B0 load with feature compute below

    // ---- compute features into persistent A: row=tid>>4, i0=(tid&15)*8 ----
    {
        int row = tid >> 4;       // 0..31
        int ip = tid & 15;        // 0..15
        const float* xr = x + (size_t)(m0 + row) * IN_DIM + ip * 8;
        float4 xa = *(const float4*)xr;
        float4 xb = *(const float4*)(xr + 4);
        float xv[8] = {xa.x, xa.y, xa.z, xa.w, xb.x, xb.y, xb.z, xb.w};
        float g0 = grid[0];
        float inv_h = 1.f / (grid[4] - grid[3]);

        short8 feat[9];
#pragma unroll
        for (int e = 0; e < 8; ++e) {
            float v = xv[e];
            float sl = v / (1.f + __expf(-v));
            int j; float w0, w1, w2, w3;
            basis_weights(v, g0, inv_h, j, w0, w1, w2, w3);
            bool inr = (j >= 0) && (j < 11);
            feat[0][e] = (short)to_bf16_bits(sl);
#pragma unroll
            for (int m = 0; m < 8; ++m) {
                int k2 = m - (j - 3);
                float val = 0.f;
                if (inr && k2 >= 0 && k2 < 4)
                    val = (k2 == 0) ? w0 : (k2 == 1) ? w1 : (k2 == 2) ? w2 : w3;
                feat[1 + m][e] = (short)to_bf16_bits(val);
            }
        }
        // chunk = (f*16 + ip) ^ (row&7): XOR stays within the f-group
#pragma unroll
        for (int f = 0; f < 9; ++f) {
            int chunk = (f * 16 + ip) ^ (row & 7);
            *(short8*)(Abase + row * 2304 + chunk * 16) = feat[f];
        }
    }
    __syncthreads();   // drains vmcnt(0): B0 staged; features visible

    // ---- K loop: wave (g, w); 32x32 tile, K-subslices ks = 2g, 2g+1 ----
    const int w = wave & 3, g = wave >> 2;
    const int r0 = lane & 15;
    const int ksub = lane >> 4;
    f32x4 acc[2][2];
#pragma unroll
    for (int rg = 0; rg < 2; ++rg)
#pragma unroll
        for (int n = 0; n < 2; ++n) acc[rg][n] = 0.f;

    int cur = 0;
    for (int t = 0; t < NT; ++t) {
        if (t + 1 < NT) stageB(cur ^ 1, t + 1);

        short8 a[2][2], b[2][2];
#pragma unroll
        for (int rg = 0; rg < 2; ++rg) {
            int row = rg * 16 + r0;
#pragma unroll
            for (int k2 = 0; k2 < 2; ++k2) {
                int c = 16 * t + (g * 2 + k2) * 4 + ksub;   // logical chunk
                int cs = c ^ (row & 7);                     // swizzled slot
                a[rg][k2] = *(const short8*)(Abase + row * 2304 + cs * 16);
            }
        }
#pragma unroll
        for (int n = 0; n < 2; ++n) {
            int o = w * 32 + n * 16 + r0;
            const char* Brow = Bbase + cur * B_TILE_BYTES + o * 256;
#pragma unroll
            for (int k2 = 0; k2 < 2; ++k2) {
                int ch = (g * 2 + k2) * 4 + ksub;
                b[n][k2] = *(const short8*)(Brow + (ch ^ (o & 7)) * 16);
            }
        }
#pragma unroll
        for (int k2 = 0; k2 < 2; ++k2)
#pragma unroll
            for (int rg = 0; rg < 2; ++rg)
#pragma unroll
                for (int n = 0; n < 2; ++n)
                    acc[rg][n] = __builtin_amdgcn_mfma_f32_16x16x32_bf16(
                        a[rg][k2], b[n][k2], acc[rg][n], 0, 0, 0);
        __syncthreads();   // next B tile staged; cur buffer free
        cur ^= 1;
    }

    // ---- ks-split reduction via LDS (reuse A region), then store ----
    // C/D map: col = lane&15, row = (lane>>4)*4 + q
    float* pane = (float*)smem;           // 4 panes of [32][33] f32
    const int pbase = w * (32 * 33);
    if (g == 1) {
#pragma unroll
        for (int rg = 0; rg < 2; ++rg)
#pragma unroll
            for (int n = 0; n < 2; ++n)
#pragma unroll
                for (int q = 0; q < 4; ++q) {
                    int row = rg * 16 + ksub * 4 + q;
                    pane[pbase + row * 33 + n * 16 + r0] = acc[rg][n][q];
                }
    }
    __syncthreads();
    if (g == 0) {
        float s = scale[0];
#pragma unroll
        for (int rg = 0; rg < 2; ++rg)
#pragma unroll
            for (int n = 0; n < 2; ++n)
#pragma unroll
                for (int q = 0; q < 4; ++q) {
                    int row = rg * 16 + ksub * 4 + q;
                    float v = acc[rg][n][q] + pane[pbase + row * 33 + n * 16 + r0];
                    out[(size_t)(m0 + row) * OUT_DIM + w * 32 + n * 16 + r0] = v * s;
                }
    }
}

// ---------------------------------------------------------------------------
// Fallback (only if ws too small): fully fused f32, correct but slow.
// ---------------------------------------------------------------------------
__global__ void k_naive(const float* __restrict__ x, const float* __restrict__ grid,
                        const float* __restrict__ C, const float* __restrict__ W,
                        const float* __restrict__ scale, float* __restrict__ out) {
    __shared__ float sS[128];
    __shared__ float sB[128][8];
    int b = blockIdx.x, t = threadIdx.x;   // 128 threads
    float xv = x[(size_t)b * IN_DIM + t];
    float g0 = grid[0];
    float inv_h = 1.f / (grid[4] - grid[3]);
    sS[t] = xv / (1.f + __expf(-xv));
    int j; float w0, w1, w2, w3;
    basis_weights(xv, g0, inv_h, j, w0, w1, w2, w3);
    bool inrange = (j >= 0) && (j < 11);
#pragma unroll
    for (int m = 0; m < 8; ++m) {
        int k2 = m - (j - 3);
        float val = 0.f;
        if (inrange && k2 >= 0 && k2 < 4)
            val = (k2 == 0) ? w0 : (k2 == 1) ? w1 : (k2 == 2) ? w2 : w3;
        sB[t][m] = val;
    }
    __syncthreads();
    float acc = 0.f;
    for (int i = 0; i < IN_DIM; ++i) {
        acc += sS[i] * W[(size_t)i * OUT_DIM + t];
        const float* c = C + ((size_t)i * OUT_DIM + t) * NB;
#pragma unroll
        for (int m = 0; m < 8; ++m) acc += sB[i][m] * c[m];
    }
    out[(size_t)b * OUT_DIM + t] = acc * scale[0];
}

// ---------------------------------------------------------------------------
extern "C" void kernel_launch(void* const* d_in, const int* in_sizes, int n_in,
                              void* d_out, int out_size, void* d_ws, size_t ws_size,
                              hipStream_t stream) {
    const float* x     = (const float*)d_in[0];
    const float* grid  = (const float*)d_in[1];
    const float* C     = (const float*)d_in[2];
    const float* W     = (const float*)d_in[3];
    const float* scale = (const float*)d_in[4];
    float* out = (float*)d_out;

    int B = in_sizes[0] / IN_DIM;   // 8192

    size_t needW = (size_t)9 * WG_TILE * sizeof(bf16); // 288 KB

    if (ws_size >= needW && (B % BM) == 0) {
        bf16* Wg = (bf16*)d_ws;
        k_wc<<<32, 256, 0, stream>>>(W, C, Wg);
        k_fused<<<B / BM, 512, 0, stream>>>(x, grid, Wg, scale, out);
    } else {
        k_naive<<<B, 128, 0, stream>>>(x, grid, C, W, scale, out);
    }
}

// Round 4
// 18.054 us; speedup vs baseline: 2.2659x; 1.1961x over previous
//
#include <hip/hip_runtime.h>
#include <hip/hip_bf16.h>
#include <cstdint>
#include <cstddef>

#define IN_DIM 128
#define OUT_DIM 128
#define NB 8
#define KDIM 1152            // K order: spline k=i*8+m (1024) ++ base k=1024+i (128)
#define BM 32
#define NT 9                 // 9 K-tiles of 128
#define B_TILE_BYTES (128 * 256)    // 128 o-rows x 256B = 32 KiB
#define A_ROW_BYTES 2304            // 1152 bf16 = 144 x 16B chunks
#define A_BYTES (BM * A_ROW_BYTES)  // 73728

using bf16 = __hip_bfloat16;
typedef __attribute__((ext_vector_type(8))) short short8;   // 8 bf16
typedef __attribute__((ext_vector_type(4))) float f32x4;

// ---------------------------------------------------------------------------
// Uniform cubic B-spline: grid knots g0..g11, spacing h. x in [g_j,g_{j+1}):
// nonzero basis m = j-3..j (clipped to [0,7]) with standard cubic weights.
// ---------------------------------------------------------------------------
__device__ __forceinline__ void basis_weights(float xv, float g0, float inv_h,
                                              int& j, float& w0, float& w1,
                                              float& w2, float& w3) {
    float t = (xv - g0) * inv_h;
    float jf = floorf(t);
    j = (int)jf;
    float u = t - jf;
    float um = 1.f - u;
    float u2 = u * u, u3 = u2 * u;
    w0 = um * um * um * (1.f / 6.f);
    w1 = (3.f * u3 - 6.f * u2 + 4.f) * (1.f / 6.f);
    w2 = (-3.f * u3 + 3.f * u2 + 3.f * u + 1.f) * (1.f / 6.f);
    w3 = u3 * (1.f / 6.f);
}

__device__ __forceinline__ unsigned short to_bf16_bits(float v) {
    bf16 h = __float2bfloat16(v);
    return *(unsigned short*)&h;
}

// ---------------------------------------------------------------------------
// Single fused kernel. Per block (BM=32 rows, 512 thr = 8 waves):
//   1. compute 32x1152 bf16 feature tile -> persistent LDS A (XOR-swizzled)
//   2. K-loop over 9 tiles of 128: B staged straight from C/W f32 (coalesced)
//      with in-register bf16 cvt + transposing XOR-swizzled ds_write
//      (double-buffered, loads issued before MFMAs = T14 split)
//   3. ks-split-2 waves: g=wave>>2 owns K-subslices, reduced via LDS panes.
// B-tile layout: [o][i_local], chunk (16B) = one i's 8 m's; swizzle ch^(o&7).
// ---------------------------------------------------------------------------
__global__ __launch_bounds__(512)
void k_kan(const float* __restrict__ x, const float* __restrict__ grid,
           const float* __restrict__ C, const float* __restrict__ W,
           const float* __restrict__ scale, float* __restrict__ out) {
    __shared__ __align__(16) char smem[A_BYTES + 2 * B_TILE_BYTES];  // 136 KiB
    char* Abase = smem;
    char* Bbase = smem + A_BYTES;

    const int tid = threadIdx.x;
    const int lane = tid & 63;
    const int m0 = blockIdx.x * BM;

    // ---- prologue: stage spline tile 0 into buf 0 (loads+cvt+write) ----
#pragma unroll
    for (int inst = 0; inst < 4; ++inst) {
        int c = inst * 512 + tid;            // 0..2047
        int o = c & 127, ch = c >> 7;        // i = ch (tile 0)
        const float* src = C + ((size_t)ch * 128 + o) * 8;
        float4 va = *(const float4*)src;
        float4 vb = *(const float4*)(src + 4);
        short8 pk;
        pk[0] = (short)to_bf16_bits(va.x); pk[1] = (short)to_bf16_bits(va.y);
        pk[2] = (short)to_bf16_bits(va.z); pk[3] = (short)to_bf16_bits(va.w);
        pk[4] = (short)to_bf16_bits(vb.x); pk[5] = (short)to_bf16_bits(vb.y);
        pk[6] = (short)to_bf16_bits(vb.z); pk[7] = (short)to_bf16_bits(vb.w);
        *(short8*)(Bbase + o * 256 + ((ch ^ (o & 7)) << 4)) = pk;
    }

    // ---- features into persistent A: thread (row=tid>>4, ip=tid&15) ----
    {
        int row = tid >> 4, ip = tid & 15;
        const float* xr = x + (size_t)(m0 + row) * IN_DIM + ip * 8;
        float4 xa = *(const float4*)xr;
        float4 xb = *(const float4*)(xr + 4);
        float xv[8] = {xa.x, xa.y, xa.z, xa.w, xb.x, xb.y, xb.z, xb.w};
        float g0 = grid[0];
        float inv_h = 1.f / (grid[4] - grid[3]);
        char* Arow = Abase + row * A_ROW_BYTES;
        short8 sil;
#pragma unroll
        for (int e = 0; e < 8; ++e) {
            float v = xv[e];
            sil[e] = (short)to_bf16_bits(v / (1.f + __expf(-v)));
            int j; float w0, w1, w2, w3;
            basis_weights(v, g0, inv_h, j, w0, w1, w2, w3);
            bool inr = (j >= 0) && (j < 11);
            short8 bas;
#pragma unroll
            for (int m = 0; m < 8; ++m) {
                int k2 = m - (j - 3);
                float val = 0.f;
                if (inr && k2 >= 0 && k2 < 4)
                    val = (k2 == 0) ? w0 : (k2 == 1) ? w1 : (k2 == 2) ? w2 : w3;
                bas[m] = (short)to_bf16_bits(val);
            }
            int chunk = (ip * 8 + e) ^ (row & 7);   // chunk i holds k=i*8+m
            *(short8*)(Arow + chunk * 16) = bas;
        }
        int chunk = (128 + ip) ^ (row & 7);         // base: silu[i0..i0+7]
        *(short8*)(Arow + chunk * 16) = sil;
    }
    __syncthreads();   // A visible; B tile 0 staged

    // ---- K loop: wave (g = tid>>8 ksplit, w = (tid>>6)&3 col-group) ----
    const int w = (tid >> 6) & 3, g = tid >> 8;
    const int r0 = lane & 15;
    const int ksub = lane >> 4;
    f32x4 acc[2][2];
#pragma unroll
    for (int rg = 0; rg < 2; ++rg)
#pragma unroll
        for (int n = 0; n < 2; ++n) acc[rg][n] = 0.f;

    int cur = 0;
    for (int t = 0; t < NT; ++t) {
        // -- issue next-tile global loads EARLY (complete under the MFMAs) --
        float4 st[4][2];
        const bool do_stage = (t + 1 < NT);
        if (do_stage) {
            if (t + 1 < 8) {                         // spline tile: 64KB of C
                int i0 = (t + 1) * 16;
#pragma unroll
                for (int inst = 0; inst < 4; ++inst) {
                    int c = inst * 512 + tid;
                    int o = c & 127, ch = c >> 7;
                    const float* src = C + ((size_t)(i0 + ch) * 128 + o) * 8;
                    st[inst][0] = *(const float4*)src;
                    st[inst][1] = *(const float4*)(src + 4);
                }
            } else {                                 // base tile: W^T gather
#pragma unroll
                for (int inst = 0; inst < 4; ++inst) {
                    int c = inst * 512 + tid;
                    int o = c & 127, ch = c >> 7;
                    float v[8];
#pragma unroll
                    for (int s = 0; s < 8; ++s)
                        v[s] = W[(size_t)(ch * 8 + s) * 128 + o];
                    st[inst][0] = make_float4(v[0], v[1], v[2], v[3]);
                    st[inst][1] = make_float4(v[4], v[5], v[6], v[7]);
                }
            }
        }

        // -- compute tile t from buf cur --
        const char* Bbuf = Bbase + cur * B_TILE_BYTES;
        short8 a[2][2], b[2][2];
#pragma unroll
        for (int rg = 0; rg < 2; ++rg) {
            int row = rg * 16 + r0;
#pragma unroll
            for (int k2 = 0; k2 < 2; ++k2) {
                int c = t * 16 + (g * 2 + k2) * 4 + ksub;
                int cs = c ^ (row & 7);
                a[rg][k2] = *(const short8*)(Abase + row * A_ROW_BYTES + cs * 16);
            }
        }
#pragma unroll
        for (int n = 0; n < 2; ++n) {
            int o = w * 32 + n * 16 + r0;
#pragma unroll
            for (int k2 = 0; k2 < 2; ++k2) {
                int ch = (g * 2 + k2) * 4 + ksub;
                b[n][k2] = *(const short8*)(Bbuf + o * 256 + ((ch ^ (o & 7)) << 4));
            }
        }
#pragma unroll
        for (int k2 = 0; k2 < 2; ++k2)
#pragma unroll
            for (int rg = 0; rg < 2; ++rg)
#pragma unroll
                for (int n = 0; n < 2; ++n)
                    acc[rg][n] = __builtin_amdgcn_mfma_f32_16x16x32_bf16(
                        a[rg][k2], b[n][k2], acc[rg][n], 0, 0, 0);

        // -- cvt + transposing ds_write of staged data (write-late) --
        if (do_stage) {
            char* Bnxt = Bbase + (cur ^ 1) * B_TILE_BYTES;
#pragma unroll
            for (int inst = 0; inst < 4; ++inst) {
                int c = inst * 512 + tid;
                int o = c & 127, ch = c >> 7;
                short8 pk;
                pk[0] = (short)to_bf16_bits(st[inst][0].x);
                pk[1] = (short)to_bf16_bits(st[inst][0].y);
                pk[2] = (short)to_bf16_bits(st[inst][0].z);
                pk[3] = (short)to_bf16_bits(st[inst][0].w);
                pk[4] = (short)to_bf16_bits(st[inst][1].x);
                pk[5] = (short)to_bf16_bits(st[inst][1].y);
                pk[6] = (short)to_bf16_bits(st[inst][1].z);
                pk[7] = (short)to_bf16_bits(st[inst][1].w);
                *(short8*)(Bnxt + o * 256 + ((ch ^ (o & 7)) << 4)) = pk;
            }
        }
        __syncthreads();
        cur ^= 1;
    }

    // ---- ks-split reduction via LDS panes (reuse A region), then store ----
    float* pane = (float*)smem;              // 4 panes of [32][33] f32
    const int pbase = w * (32 * 33);
    if (g == 1) {
#pragma unroll
        for (int rg = 0; rg < 2; ++rg)
#pragma unroll
            for (int n = 0; n < 2; ++n)
#pragma unroll
                for (int q = 0; q < 4; ++q) {
                    int row = rg * 16 + ksub * 4 + q;
                    pane[pbase + row * 33 + n * 16 + r0] = acc[rg][n][q];
                }
    }
    __syncthreads();
    if (g == 0) {
        float s = scale[0];
#pragma unroll
        for (int rg = 0; rg < 2; ++rg)
#pragma unroll
            for (int n = 0; n < 2; ++n)
#pragma unroll
                for (int q = 0; q < 4; ++q) {
                    int row = rg * 16 + ksub * 4 + q;
                    float v = acc[rg][n][q] + pane[pbase + row * 33 + n * 16 + r0];
                    out[(size_t)(m0 + row) * OUT_DIM + w * 32 + n * 16 + r0] = v * s;
                }
    }
}

// ---------------------------------------------------------------------------
// Fallback: fully fused f32, correct but slow (only if B % 32 != 0).
// ---------------------------------------------------------------------------
__global__ void k_naive(const float* __restrict__ x, const float* __restrict__ grid,
                        const float* __restrict__ C, const float* __restrict__ W,
                        const float* __restrict__ scale, float* __restrict__ out) {
    __shared__ float sS[128];
    __shared__ float sB[128][8];
    int b = blockIdx.x, t = threadIdx.x;   // 128 threads
    float xv = x[(size_t)b * IN_DIM + t];
    float g0 = grid[0];
    float inv_h = 1.f / (grid[4] - grid[3]);
    sS[t] = xv / (1.f + __expf(-xv));
    int j; float w0, w1, w2, w3;
    basis_weights(xv, g0, inv_h, j, w0, w1, w2, w3);
    bool inrange = (j >= 0) && (j < 11);
#pragma unroll
    for (int m = 0; m < 8; ++m) {
        int k2 = m - (j - 3);
        float val = 0.f;
        if (inrange && k2 >= 0 && k2 < 4)
            val = (k2 == 0) ? w0 : (k2 == 1) ? w1 : (k2 == 2) ? w2 : w3;
        sB[t][m] = val;
    }
    __syncthreads();
    float acc = 0.f;
    for (int i = 0; i < IN_DIM; ++i) {
        acc += sS[i] * W[(size_t)i * OUT_DIM + t];
        const float* c = C + ((size_t)i * OUT_DIM + t) * NB;
#pragma unroll
        for (int m = 0; m < 8; ++m) acc += sB[i][m] * c[m];
    }
    out[(size_t)b * OUT_DIM + t] = acc * scale[0];
}

// ---------------------------------------------------------------------------
extern "C" void kernel_launch(void* const* d_in, const int* in_sizes, int n_in,
                              void* d_out, int out_size, void* d_ws, size_t ws_size,
                              hipStream_t stream) {
    const float* x     = (const float*)d_in[0];
    const float* grid  = (const float*)d_in[1];
    const float* C     = (const float*)d_in[2];
    const float* W     = (const float*)d_in[3];
    const float* scale = (const float*)d_in[4];
    float* out = (float*)d_out;

    int B = in_sizes[0] / IN_DIM;   // 8192

    if ((B % BM) == 0) {
        k_kan<<<B / BM, 512, 0, stream>>>(x, grid, C, W, scale, out);
    } else {
        k_naive<<<B, 128, 0, stream>>>(x, grid, C, W, scale, out);
    }
}

// Round 6
// 16.352 us; speedup vs baseline: 2.5017x; 1.1041x over previous
//
#include <hip/hip_runtime.h>
#include <hip/hip_bf16.h>
#include <cstdint>
#include <cstddef>

#define IN_DIM 128
#define OUT_DIM 128
#define NB 8
#define BM 32
#define NT 9                        // 9 K-tiles of 128; K order: spline k=i*8+m, base k=1024+i
#define A_ROW_BYTES 2304            // 1152 bf16 = 144 x 16B chunks
#define A_BYTES (BM * A_ROW_BYTES)  // 73728

using bf16 = __hip_bfloat16;
typedef __attribute__((ext_vector_type(8))) short short8;   // 8 bf16
typedef __attribute__((ext_vector_type(4))) float f32x4;

// ---------------------------------------------------------------------------
// Uniform cubic B-spline: grid knots g0..g11, spacing h. x in [g_j,g_{j+1}):
// nonzero basis m = j-3..j (clipped to [0,7]) with standard cubic weights.
// ---------------------------------------------------------------------------
__device__ __forceinline__ void basis_weights(float xv, float g0, float inv_h,
                                              int& j, float& w0, float& w1,
                                              float& w2, float& w3) {
    float t = (xv - g0) * inv_h;
    float jf = floorf(t);
    j = (int)jf;
    float u = t - jf;
    float um = 1.f - u;
    float u2 = u * u, u3 = u2 * u;
    w0 = um * um * um * (1.f / 6.f);
    w1 = (3.f * u3 - 6.f * u2 + 4.f) * (1.f / 6.f);
    w2 = (-3.f * u3 + 3.f * u2 + 3.f * u + 1.f) * (1.f / 6.f);
    w3 = u3 * (1.f / 6.f);
}

__device__ __forceinline__ unsigned short to_bf16_bits(float v) {
    bf16 h = __float2bfloat16(v);
    return *(unsigned short*)&h;
}

__device__ __forceinline__ short8 pack8(const float4& a, const float4& b) {
    short8 p;
    p[0] = (short)to_bf16_bits(a.x); p[1] = (short)to_bf16_bits(a.y);
    p[2] = (short)to_bf16_bits(a.z); p[3] = (short)to_bf16_bits(a.w);
    p[4] = (short)to_bf16_bits(b.x); p[5] = (short)to_bf16_bits(b.y);
    p[6] = (short)to_bf16_bits(b.z); p[7] = (short)to_bf16_bits(b.w);
    return p;
}

// ---------------------------------------------------------------------------
// Single fused kernel, barrier-free K-loop.
// Per block (BM=32 rows, 512 thr = 8 waves = (g:2 ksplit) x (w:4 col-groups)):
//   1. issue tile-0 B-frag loads; compute 32x1152 bf16 feature tile into
//      persistent XOR-swizzled LDS A; one barrier.
//   2. fully-unrolled K-loop: B-fragments loaded straight from C (f32,
//      coalesced 32B/lane) into regs w/ depth-1 prefetch, cvt to bf16,
//      A-frags via ds_read_b128, 8 MFMAs/wave/tile. No syncthreads.
//   3. ks-split reduction via LDS panes, store.
// ---------------------------------------------------------------------------
__global__ __launch_bounds__(512)
void k_kan(const float* __restrict__ x, const float* __restrict__ grid,
           const float* __restrict__ C, const float* __restrict__ W,
           const float* __restrict__ scale, float* __restrict__ out) {
    __shared__ __align__(16) char smem[A_BYTES];   // 73.7 KiB

    const int tid = threadIdx.x;
    const int lane = tid & 63;
    const int m0 = blockIdx.x * BM;
    const int w = (tid >> 6) & 3;      // col-group: cols w*32..+31
    const int g = tid >> 8;            // k-split half
    const int r0 = lane & 15;
    const int ksub = lane >> 4;

    int ocol[2];                       // frag columns
    ocol[0] = w * 32 + r0;
    ocol[1] = w * 32 + 16 + r0;

    float4 cb[2][2][2];                // current tile f32 [k2][n][half]
    float4 pf[2][2][2];                // prefetch regs

    auto load_spline = [&](int t, float4 (&dst)[2][2][2]) {
#pragma unroll
        for (int k2 = 0; k2 < 2; ++k2) {
            int i = t * 16 + (2 * g + k2) * 4 + ksub;
#pragma unroll
            for (int n = 0; n < 2; ++n) {
                const float* src = C + ((size_t)i * 128 + ocol[n]) * 8;
                dst[k2][n][0] = *(const float4*)src;
                dst[k2][n][1] = *(const float4*)(src + 4);
            }
        }
    };
    auto load_base = [&](float4 (&dst)[2][2][2]) {
#pragma unroll
        for (int k2 = 0; k2 < 2; ++k2) {
            int ibase = (2 * g + k2) * 32 + ksub * 8;
#pragma unroll
            for (int n = 0; n < 2; ++n) {
                float v[8];
#pragma unroll
                for (int e = 0; e < 8; ++e)
                    v[e] = W[(size_t)(ibase + e) * 128 + ocol[n]];
                dst[k2][n][0] = make_float4(v[0], v[1], v[2], v[3]);
                dst[k2][n][1] = make_float4(v[4], v[5], v[6], v[7]);
            }
        }
    };

    load_spline(0, cb);   // in flight under the feature-compute prologue

    // ---- features into persistent A: thread (row=tid>>4, ip=tid&15) ----
    {
        int row = tid >> 4, ip = tid & 15;
        const float* xr = x + (size_t)(m0 + row) * IN_DIM + ip * 8;
        float4 xa = *(const float4*)xr;
        float4 xb = *(const float4*)(xr + 4);
        float xv[8] = {xa.x, xa.y, xa.z, xa.w, xb.x, xb.y, xb.z, xb.w};
        float g0 = grid[0];
        float inv_h = 1.f / (grid[4] - grid[3]);
        char* Arow = smem + row * A_ROW_BYTES;
        short8 sil;
#pragma unroll
        for (int e = 0; e < 8; ++e) {
            float v = xv[e];
            sil[e] = (short)to_bf16_bits(v / (1.f + __expf(-v)));
            int j; float w0, w1, w2, w3;
            basis_weights(v, g0, inv_h, j, w0, w1, w2, w3);
            bool inr = (j >= 0) && (j < 11);
            short8 bas;
#pragma unroll
            for (int m = 0; m < 8; ++m) {
                int k2 = m - (j - 3);
                float val = 0.f;
                if (inr && k2 >= 0 && k2 < 4)
                    val = (k2 == 0) ? w0 : (k2 == 1) ? w1 : (k2 == 2) ? w2 : w3;
                bas[m] = (short)to_bf16_bits(val);
            }
            int chunk = (ip * 8 + e) ^ (row & 7);   // chunk i holds k=i*8+m
            *(short8*)(Arow + chunk * 16) = bas;
        }
        int chunk = (128 + ip) ^ (row & 7);         // base: silu[i0..i0+7]
        *(short8*)(Arow + chunk * 16) = sil;
    }
    __syncthreads();   // the only barrier before the epilogue

    f32x4 acc[2][2];
#pragma unroll
    for (int rg = 0; rg < 2; ++rg)
#pragma unroll
        for (int n = 0; n < 2; ++n) acc[rg][n] = 0.f;

    // ---- barrier-free K loop (fully unrolled; static register rotation) ----
#pragma unroll
    for (int t = 0; t < NT; ++t) {
        if (t + 1 < 8)        load_spline(t + 1, pf);
        else if (t + 1 == 8)  load_base(pf);

        short8 b[2][2];
#pragma unroll
        for (int k2 = 0; k2 < 2; ++k2)
#pragma unroll
            for (int n = 0; n < 2; ++n)
                b[k2][n] = pack8(cb[k2][n][0], cb[k2][n][1]);

        short8 a[2][2];
#pragma unroll
        for (int rg = 0; rg < 2; ++rg) {
            int row = rg * 16 + r0;
#pragma unroll
            for (int k2 = 0; k2 < 2; ++k2) {
                int c = t * 16 + (2 * g + k2) * 4 + ksub;
                int cs = c ^ (row & 7);
                a[rg][k2] = *(const short8*)(smem + row * A_ROW_BYTES + cs * 16);
            }
        }
#pragma unroll
        for (int k2 = 0; k2 < 2; ++k2)
#pragma unroll
            for (int rg = 0; rg < 2; ++rg)
#pragma unroll
                for (int n = 0; n < 2; ++n)
                    acc[rg][n] = __builtin_amdgcn_mfma_f32_16x16x32_bf16(
                        a[rg][k2], b[k2][n], acc[rg][n], 0, 0, 0);

        if (t + 1 < NT) {
#pragma unroll
            for (int k2 = 0; k2 < 2; ++k2)
#pragma unroll
                for (int n = 0; n < 2; ++n)
#pragma unroll
                    for (int h = 0; h < 2; ++h)
                        cb[k2][n][h] = pf[k2][n][h];
        }
    }

    // ---- ks-split reduction via LDS panes (A region reused), then store ----
    __syncthreads();   // all A reads done before panes overwrite the region
    float* pane = (float*)smem;              // 4 panes of [32][33] f32
    const int pbase = w * (32 * 33);
    if (g == 1) {
#pragma unroll
        for (int rg = 0; rg < 2; ++rg)
#pragma unroll
            for (int n = 0; n < 2; ++n)
#pragma unroll
                for (int q = 0; q < 4; ++q) {
                    int row = rg * 16 + ksub * 4 + q;
                    pane[pbase + row * 33 + n * 16 + r0] = acc[rg][n][q];
                }
    }
    __syncthreads();
    if (g == 0) {
        float s = scale[0];
#pragma unroll
        for (int rg = 0; rg < 2; ++rg)
#pragma unroll
            for (int n = 0; n < 2; ++n)
#pragma unroll
                for (int q = 0; q < 4; ++q) {
                    int row = rg * 16 + ksub * 4 + q;
                    float v = acc[rg][n][q] + pane[pbase + row * 33 + n * 16 + r0];
                    out[(size_t)(m0 + row) * OUT_DIM + w * 32 + n * 16 + r0] = v * s;
                }
    }
}

// ---------------------------------------------------------------------------
// Fallback: fully fused f32, correct but slow (only if B % 32 != 0).
// ---------------------------------------------------------------------------
__global__ void k_naive(const float* __restrict__ x, const float* __restrict__ grid,
                        const float* __restrict__ C, const float* __restrict__ W,
                        const float* __restrict__ scale, float* __restrict__ out) {
    __shared__ float sS[128];
    __shared__ float sB[128][8];
    int b = blockIdx.x, t = threadIdx.x;   // 128 threads
    float xv = x[(size_t)b * IN_DIM + t];
    float g0 = grid[0];
    float inv_h = 1.f / (grid[4] - grid[3]);
    sS[t] = xv / (1.f + __expf(-xv));
    int j; float w0, w1, w2, w3;
    basis_weights(xv, g0, inv_h, j, w0, w1, w2, w3);
    bool inrange = (j >= 0) && (j < 11);
#pragma unroll
    for (int m = 0; m < 8; ++m) {
        int k2 = m - (j - 3);
        float val = 0.f;
        if (inrange && k2 >= 0 && k2 < 4)
            val = (k2 == 0) ? w0 : (k2 == 1) ? w1 : (k2 == 2) ? w2 : w3;
        sB[t][m] = val;
    }
    __syncthreads();
    float acc = 0.f;
    for (int i = 0; i < IN_DIM; ++i) {
        acc += sS[i] * W[(size_t)i * OUT_DIM + t];
        const float* c = C + ((size_t)i * OUT_DIM + t) * NB;
#pragma unroll
        for (int m = 0; m < 8; ++m) acc += sB[i][m] * c[m];
    }
    out[(size_t)b * OUT_DIM + t] = acc * scale[0];
}

// ---------------------------------------------------------------------------
extern "C" void kernel_launch(void* const* d_in, const int* in_sizes, int n_in,
                              void* d_out, int out_size, void* d_ws, size_t ws_size,
                              hipStream_t stream) {
    const float* x     = (const float*)d_in[0];
    const float* grid  = (const float*)d_in[1];
    const float* C     = (const float*)d_in[2];
    const float* W     = (const float*)d_in[3];
    const float* scale = (const float*)d_in[4];
    float* out = (float*)d_out;

    int B = in_sizes[0] / IN_DIM;   // 8192

    if ((B % BM) == 0) {
        k_kan<<<B / BM, 512, 0, stream>>>(x, grid, C, W, scale, out);
    } else {
        k_naive<<<B, 128, 0, stream>>>(x, grid, C, W, scale, out);
    }
}